// Round 3
// baseline (229.116 us; speedup 1.0000x reference)
//
#include <hip/hip_runtime.h>
#include <stdint.h>

#define BS 8
#define V 4096
#define C 64
#define A 12
#define POOL 1024

// orderable-uint transform: monotone bijection f32 -> u32 (u(a)<u(b) <=> a<b)
__device__ inline unsigned int ordu(float f) {
    unsigned int b = __float_as_uint(f);
    return b ^ ((unsigned int)(((int)b) >> 31) | 0x80000000u);
}
__device__ inline float unordu(unsigned int u) {
    unsigned int m = (~((unsigned int)(((int)u) >> 31))) | 0x80000000u;
    return __uint_as_float(u ^ m);
}

// ---------------------------------------------------------------------------
// Kernel 1: per-(batch, query-chunk, candidate-chunk) partial top-5.
// Also zeroes the per-(b,j) reference counters (blocks 0..127).
// ---------------------------------------------------------------------------
template<int NCC>
__global__ __launch_bounds__(256) void knn_chunk_kernel(
    const float* __restrict__ vtx,                 // [BS][V][3]
    const int* __restrict__ sidx,                  // [POOL]
    unsigned long long* __restrict__ partial,      // [BS*POOL][NCC*5]
    unsigned int* __restrict__ counts)             // [BS*V]
{
    constexpr int CC = V / NCC;
    __shared__ float4 cand[CC];

    const int bid = blockIdx.x;
    const int tid = threadIdx.x;
    if (bid < (BS * V) / 256) counts[bid * 256 + tid] = 0;

    const int cc = bid % NCC;
    const int qc = (bid / NCC) & 3;        // NQC = 4
    const int b  = bid / (NCC * 4);

    const float* vb = vtx + (size_t)b * V * 3;

    for (int t = tid; t < CC; t += 256) {
        const int j = cc * CC + t;
        const float x = vb[j * 3 + 0];
        const float y = vb[j * 3 + 1];
        const float z = vb[j * 3 + 2];
        float q;
        {
#pragma clang fp contract(off)
            q = (x * x + y * y) + z * z;   // match XLA: elementwise mul, then sum
        }
        cand[t] = make_float4(x, y, z, q);
    }
    __syncthreads();

    const int s = qc * 256 + tid;
    const int gq = sidx[s];
    const float qx = vb[gq * 3 + 0];
    const float qy = vb[gq * 3 + 1];
    const float qz = vb[gq * 3 + 2];
    float qq;
    {
#pragma clang fp contract(off)
        qq = (qx * qx + qy * qy) + qz * qz;
    }

    unsigned int h0 = ~0u, h1 = ~0u, h2 = ~0u, h3 = ~0u, h4 = ~0u;
    unsigned int l0 = 0, l1 = 0, l2 = 0, l3 = 0, l4 = 0;

#pragma unroll 8
    for (int jj = 0; jj < CC; ++jj) {
        const float4 cd = cand[jj];
        const float inner = fmaf(cd.z, qz, fmaf(cd.y, qy, cd.x * qx));
        const float d = fmaf(-2.0f, inner, cd.w) + qq;   // -2*inner exact
        const unsigned int bits = __float_as_uint(d);
        const unsigned int u = bits ^ ((unsigned int)(((int)bits) >> 31) | 0x80000000u);
        const unsigned int idx = (unsigned int)(cc * CC + jj);
        if (u < h4) {   // strict: ties lose to smaller stored idx
            const bool c0 = u < h0, c1 = u < h1, c2 = u < h2, c3 = u < h3;
            h4 = c3 ? h3 : u;              l4 = c3 ? l3 : idx;
            h3 = c3 ? (c2 ? h2 : u) : h3;  l3 = c3 ? (c2 ? l2 : idx) : l3;
            h2 = c2 ? (c1 ? h1 : u) : h2;  l2 = c2 ? (c1 ? l1 : idx) : l2;
            h1 = c1 ? (c0 ? h0 : u) : h1;  l1 = c1 ? (c0 ? l0 : idx) : l1;
            h0 = c0 ? u : h0;              l0 = c0 ? idx : l0;
        }
    }

    unsigned long long* p = partial + ((size_t)(b * POOL + s) * NCC + cc) * 5;
    p[0] = ((unsigned long long)h0 << 32) | l0;
    p[1] = ((unsigned long long)h1 << 32) | l1;
    p[2] = ((unsigned long long)h2 << 32) | l2;
    p[3] = ((unsigned long long)h3 << 32) | l3;
    p[4] = ((unsigned long long)h4 << 32) | l4;
}

// ---------------------------------------------------------------------------
// Kernel 2: merge NCC sorted 5-lists -> top-5, drop rank 0 (self), write nbr
// + vertices_pool. Also bump per-(b,j) reference counters for the CSR build.
// ---------------------------------------------------------------------------
template<int NCC>
__global__ __launch_bounds__(256) void knn_merge_kernel(
    const unsigned long long* __restrict__ partial,  // [BS*POOL][NCC*5]
    const float* __restrict__ vtx,                   // [BS][V][3]
    const int* __restrict__ sidx,                    // [POOL]
    int* __restrict__ nbr,                           // [BS*POOL][4]
    float* __restrict__ outv,                        // [BS][POOL][3]
    unsigned int* __restrict__ counts)               // [BS*V]
{
    const int t = blockIdx.x * 256 + threadIdx.x;    // 0..BS*POOL-1
    const int b = t / POOL;
    const int s = t % POOL;

    const unsigned long long* p = partial + (size_t)t * (NCC * 5);

    unsigned int h0 = ~0u, h1 = ~0u, h2 = ~0u, h3 = ~0u, h4 = ~0u;
    unsigned int l0 = 0, l1 = 0, l2 = 0, l3 = 0, l4 = 0;

#pragma unroll 4
    for (int ccc = 0; ccc < NCC; ++ccc) {
        const unsigned long long a0 = p[ccc * 5 + 0];
        const unsigned long long a1 = p[ccc * 5 + 1];
        const unsigned long long a2 = p[ccc * 5 + 2];
        const unsigned long long a3 = p[ccc * 5 + 3];
        const unsigned long long a4 = p[ccc * 5 + 4];
        if ((unsigned int)(a0 >> 32) < h4) {
#define INS(K)                                                               \
            {                                                                \
                const unsigned int u = (unsigned int)((K) >> 32);            \
                const unsigned int idx = (unsigned int)(K);                  \
                const bool c0 = u < h0, c1 = u < h1, c2 = u < h2,            \
                           c3 = u < h3, c4 = u < h4;                         \
                h4 = c4 ? (c3 ? h3 : u) : h4;                                \
                l4 = c4 ? (c3 ? l3 : idx) : l4;                              \
                h3 = c3 ? (c2 ? h2 : u) : h3;                                \
                l3 = c3 ? (c2 ? l2 : idx) : l3;                              \
                h2 = c2 ? (c1 ? h1 : u) : h2;                                \
                l2 = c2 ? (c1 ? l1 : idx) : l2;                              \
                h1 = c1 ? (c0 ? h0 : u) : h1;                                \
                l1 = c1 ? (c0 ? l0 : idx) : l1;                              \
                h0 = c0 ? u : h0;                                            \
                l0 = c0 ? idx : l0;                                          \
            }
            INS(a0) INS(a1) INS(a2) INS(a3) INS(a4)
#undef INS
        }
    }

    int4 nb;
    nb.x = (int)l1;
    nb.y = (int)l2;
    nb.z = (int)l3;
    nb.w = (int)l4;
    ((int4*)nbr)[t] = nb;

    unsigned int* cb = counts + b * V;
    atomicAdd(&cb[l1], 1u);
    atomicAdd(&cb[l2], 1u);
    atomicAdd(&cb[l3], 1u);
    atomicAdd(&cb[l4], 1u);

    const int gq = sidx[s];
    const float* vv = vtx + ((size_t)b * V + gq) * 3;
    outv[(size_t)t * 3 + 0] = vv[0];
    outv[(size_t)t * 3 + 1] = vv[1];
    outv[(size_t)t * 3 + 2] = vv[2];
}

// ---------------------------------------------------------------------------
// Kernel 3: per-batch exclusive scan of counts -> rowptr; init cursors.
// One block per batch; 256 threads x 16 elems.
// ---------------------------------------------------------------------------
__global__ __launch_bounds__(256) void scan_kernel(
    const unsigned int* __restrict__ counts,   // [BS][V]
    unsigned int* __restrict__ rowptr,         // [BS][V+1]
    unsigned int* __restrict__ cursors)        // [BS][V]
{
    const int b = blockIdx.x;
    const int tid = threadIdx.x;
    __shared__ unsigned int psum[256];

    const unsigned int* cb = counts + b * V;
    unsigned int local[16];
    unsigned int sum = 0;
#pragma unroll
    for (int i = 0; i < 16; ++i) { local[i] = sum; sum += cb[tid * 16 + i]; }
    psum[tid] = sum;
    __syncthreads();

    for (int off = 1; off < 256; off <<= 1) {
        unsigned int v = (tid >= off) ? psum[tid - off] : 0u;
        __syncthreads();
        psum[tid] += v;
        __syncthreads();
    }
    const unsigned int base = (tid == 0) ? 0u : psum[tid - 1];

    unsigned int* rp = rowptr + b * (V + 1);
    unsigned int* cu = cursors + b * V;
#pragma unroll
    for (int i = 0; i < 16; ++i) {
        const unsigned int e = base + local[i];
        rp[tid * 16 + i] = e;
        cu[tid * 16 + i] = e;
    }
    if (tid == 255) rp[V] = base + sum;   // == 4096
}

// ---------------------------------------------------------------------------
// Kernel 4: fill CSR entries: for each (b,s) scatter s into its 4 neighbors'
// buckets. Order within a bucket is non-deterministic; max is order-invariant.
// ---------------------------------------------------------------------------
__global__ __launch_bounds__(256) void fill_kernel(
    const int* __restrict__ nbr,               // [BS*POOL][4]
    unsigned int* __restrict__ cursors,        // [BS][V]
    unsigned int* __restrict__ entries)        // [BS][4096]
{
    const int t = blockIdx.x * 256 + threadIdx.x;
    const int b = t / POOL;
    const unsigned int s = (unsigned int)(t % POOL);
    const int4 nb = ((const int4*)nbr)[t];
    unsigned int* cu = cursors + b * V;
    unsigned int* en = entries + b * 4096;
    en[atomicAdd(&cu[nb.x], 1u)] = s;
    en[atomicAdd(&cu[nb.y], 1u)] = s;
    en[atomicAdd(&cu[nb.z], 1u)] = s;
    en[atomicAdd(&cu[nb.w], 1u)] = s;
}

// ---------------------------------------------------------------------------
// Kernel 5: streaming scatter-max pool. Block = (b,c) plane; LDS holds the
// [POOL][A] output plane as orderable uints. Rows read in ascending-j order
// (stride-48B float4 lanes -> minimal line transactions); unreferenced rows
// skipped (exec-masked lanes fetch nothing).
// ---------------------------------------------------------------------------
__global__ __launch_bounds__(512) void pool_kernel(
    const float* __restrict__ fm,              // [BS][C][V][A]
    const unsigned int* __restrict__ rowptr,   // [BS][V+1]
    const unsigned int* __restrict__ entries,  // [BS][4096]
    float* __restrict__ outf)                  // [BS][C][POOL][A]
{
    __shared__ unsigned int pl[POOL * A];      // 48 KiB
    const int c = blockIdx.x % C;
    const int b = blockIdx.x / C;
    const int tid = threadIdx.x;

    {
        uint4* p4 = (uint4*)pl;
        const uint4 z = make_uint4(0u, 0u, 0u, 0u);   // 0 < ordu(any float)
#pragma unroll
        for (int i = 0; i < 6; ++i) p4[tid + i * 512] = z;
    }
    __syncthreads();

    const unsigned int* rp = rowptr + b * (V + 1);
    const unsigned int* en = entries + b * 4096;
    const float4* plane = (const float4*)(fm + (size_t)(b * C + c) * V * A);

#pragma unroll 1
    for (int it = 0; it < V / 512; ++it) {
        const int j = it * 512 + tid;
        const unsigned int beg = rp[j];
        const unsigned int end = rp[j + 1];
        if (beg == end) continue;

        const float4 f0 = plane[j * 3 + 0];
        const float4 f1 = plane[j * 3 + 1];
        const float4 f2 = plane[j * 3 + 2];
        const unsigned int u0 = ordu(f0.x), u1 = ordu(f0.y), u2  = ordu(f0.z), u3  = ordu(f0.w);
        const unsigned int u4 = ordu(f1.x), u5 = ordu(f1.y), u6  = ordu(f1.z), u7  = ordu(f1.w);
        const unsigned int u8 = ordu(f2.x), u9 = ordu(f2.y), u10 = ordu(f2.z), u11 = ordu(f2.w);

        for (unsigned int e = beg; e < end; ++e) {
            unsigned int* d = pl + en[e] * A;
            atomicMax(d + 0, u0);  atomicMax(d + 1, u1);  atomicMax(d + 2, u2);
            atomicMax(d + 3, u3);  atomicMax(d + 4, u4);  atomicMax(d + 5, u5);
            atomicMax(d + 6, u6);  atomicMax(d + 7, u7);  atomicMax(d + 8, u8);
            atomicMax(d + 9, u9);  atomicMax(d + 10, u10); atomicMax(d + 11, u11);
        }
    }
    __syncthreads();

    const uint4* p4 = (const uint4*)pl;
    float4* dst = (float4*)(outf + (size_t)(b * C + c) * POOL * A);
#pragma unroll
    for (int i = 0; i < 6; ++i) {
        const uint4 v = p4[tid + i * 512];
        float4 f;
        f.x = unordu(v.x); f.y = unordu(v.y); f.z = unordu(v.z); f.w = unordu(v.w);
        dst[tid + i * 512] = f;
    }
}

// ---------------------------------------------------------------------------
extern "C" void kernel_launch(void* const* d_in, const int* in_sizes, int n_in,
                              void* d_out, int out_size, void* d_ws, size_t ws_size,
                              hipStream_t stream) {
    const float* vtx = (const float*)d_in[0];   // vertices  [BS][V][3]
    const float* fm  = (const float*)d_in[1];   // feature_map [BS][C][V][A]
    const int* sidx  = (const int*)d_in[2];     // sample_idx [POOL]
    float* out = (float*)d_out;

    float* outv = out;                          // [BS][POOL][3]
    float* outf = out + (size_t)BS * POOL * 3;  // [BS][C][POOL][A]

    char* ws = (char*)d_ws;
    const size_t partial32_b = (size_t)BS * POOL * 32 * 5 * 8;   // 10.5 MB
    const size_t partial16_b = (size_t)BS * POOL * 16 * 5 * 8;   // 5.2 MB
    const size_t nbr_b     = (size_t)BS * POOL * 4 * 4;          // 128 KB
    const size_t counts_b  = (size_t)BS * V * 4;                 // 128 KB
    const size_t rowptr_b  = (size_t)BS * (V + 1) * 4 + 28;      // pad to 16B
    const size_t cursors_b = (size_t)BS * V * 4;
    const size_t entries_b = (size_t)BS * 4096 * 4;
    const size_t tail_b = nbr_b + counts_b + rowptr_b + cursors_b + entries_b;

    const bool big = ws_size >= partial32_b + tail_b;
    const size_t partial_b = big ? partial32_b : partial16_b;

    unsigned long long* partial = (unsigned long long*)ws;
    int* nbr            = (int*)(ws + partial_b);
    unsigned int* counts  = (unsigned int*)(ws + partial_b + nbr_b);
    unsigned int* rowptr  = (unsigned int*)(ws + partial_b + nbr_b + counts_b);
    unsigned int* cursors = (unsigned int*)(ws + partial_b + nbr_b + counts_b + rowptr_b);
    unsigned int* entries = (unsigned int*)(ws + partial_b + nbr_b + counts_b + rowptr_b + cursors_b);

    if (big) {
        constexpr int NCC = 32;
        knn_chunk_kernel<NCC><<<BS * 4 * NCC, 256, 0, stream>>>(vtx, sidx, partial, counts);
        knn_merge_kernel<NCC><<<(BS * POOL) / 256, 256, 0, stream>>>(partial, vtx, sidx, nbr, outv, counts);
    } else {
        constexpr int NCC = 16;
        knn_chunk_kernel<NCC><<<BS * 4 * NCC, 256, 0, stream>>>(vtx, sidx, partial, counts);
        knn_merge_kernel<NCC><<<(BS * POOL) / 256, 256, 0, stream>>>(partial, vtx, sidx, nbr, outv, counts);
    }
    scan_kernel<<<BS, 256, 0, stream>>>(counts, rowptr, cursors);
    fill_kernel<<<(BS * POOL) / 256, 256, 0, stream>>>(nbr, cursors, entries);
    pool_kernel<<<BS * C, 512, 0, stream>>>(fm, rowptr, entries, outf);
}

// Round 4
// 226.916 us; speedup vs baseline: 1.0097x; 1.0097x over previous
//
#include <hip/hip_runtime.h>
#include <stdint.h>

#define BS 8
#define V 4096
#define C 64
#define A 12
#define POOL 1024
#define PSTRIDE 13   // LDS row stride for pool plane: gcd(13,32)=1 -> conflict-free

// orderable-uint transform: monotone bijection f32 -> u32 (u(a)<u(b) <=> a<b)
__device__ inline unsigned int ordu(float f) {
    unsigned int b = __float_as_uint(f);
    return b ^ ((unsigned int)(((int)b) >> 31) | 0x80000000u);
}
__device__ inline float unordu(unsigned int u) {
    unsigned int m = (~((unsigned int)(((int)u) >> 31))) | 0x80000000u;
    return __uint_as_float(u ^ m);
}

// ---------------------------------------------------------------------------
// Kernel 1: per-(batch, query-chunk, candidate-chunk) partial top-5.
// Top-5 kept as plain floats (strict < preserves (dist asc, idx asc) order
// because scan index is monotone); converted to orderable bits at store.
// Also zeroes the per-(b,j) reference counters (blocks 0..127).
// ---------------------------------------------------------------------------
template<int NCC>
__global__ __launch_bounds__(256) void knn_chunk_kernel(
    const float* __restrict__ vtx,                 // [BS][V][3]
    const int* __restrict__ sidx,                  // [POOL]
    unsigned long long* __restrict__ partial,      // [BS*POOL][NCC*5]
    unsigned int* __restrict__ counts)             // [BS*V]
{
    constexpr int CC = V / NCC;
    __shared__ float4 cand[CC];

    const int bid = blockIdx.x;
    const int tid = threadIdx.x;
    if (bid < (BS * V) / 256) counts[bid * 256 + tid] = 0;

    const int cc = bid % NCC;
    const int qc = (bid / NCC) & 3;        // NQC = 4
    const int b  = bid / (NCC * 4);

    const float* vb = vtx + (size_t)b * V * 3;

    for (int t = tid; t < CC; t += 256) {
        const int j = cc * CC + t;
        const float x = vb[j * 3 + 0];
        const float y = vb[j * 3 + 1];
        const float z = vb[j * 3 + 2];
        float q;
        {
#pragma clang fp contract(off)
            q = (x * x + y * y) + z * z;   // match XLA: elementwise mul, then sum
        }
        cand[t] = make_float4(x, y, z, q);
    }
    __syncthreads();

    const int s = qc * 256 + tid;
    const int gq = sidx[s];
    const float qx = vb[gq * 3 + 0];
    const float qy = vb[gq * 3 + 1];
    const float qz = vb[gq * 3 + 2];
    float qq;
    {
#pragma clang fp contract(off)
        qq = (qx * qx + qy * qy) + qz * qz;
    }

    const float INF = __uint_as_float(0x7F800000u);
    float d0 = INF, d1 = INF, d2 = INF, d3 = INF, d4 = INF;
    unsigned int l0 = 0, l1 = 0, l2 = 0, l3 = 0, l4 = 0;

#pragma unroll 8
    for (int jj = 0; jj < CC; ++jj) {
        const float4 cd = cand[jj];
        const float inner = fmaf(cd.z, qz, fmaf(cd.y, qy, cd.x * qx));
        const float d = fmaf(-2.0f, inner, cd.w) + qq;   // -2*inner exact
        const unsigned int idx = (unsigned int)(cc * CC + jj);
        if (d < d4) {   // strict: ties lose to smaller stored idx
            const bool c0 = d < d0, c1 = d < d1, c2 = d < d2, c3 = d < d3;
            d4 = c3 ? d3 : d;              l4 = c3 ? l3 : idx;
            d3 = c3 ? (c2 ? d2 : d) : d3;  l3 = c3 ? (c2 ? l2 : idx) : l3;
            d2 = c2 ? (c1 ? d1 : d) : d2;  l2 = c2 ? (c1 ? l1 : idx) : l2;
            d1 = c1 ? (c0 ? d0 : d) : d1;  l1 = c1 ? (c0 ? l0 : idx) : l1;
            d0 = c0 ? d : d0;              l0 = c0 ? idx : l0;
        }
    }

    unsigned long long* p = partial + ((size_t)(b * POOL + s) * NCC + cc) * 5;
    p[0] = ((unsigned long long)ordu(d0) << 32) | l0;
    p[1] = ((unsigned long long)ordu(d1) << 32) | l1;
    p[2] = ((unsigned long long)ordu(d2) << 32) | l2;
    p[3] = ((unsigned long long)ordu(d3) << 32) | l3;
    p[4] = ((unsigned long long)ordu(d4) << 32) | l4;
}

// ---------------------------------------------------------------------------
// Kernel 2: merge NCC sorted 5-lists -> top-5, drop rank 0 (self), write nbr
// + vertices_pool. Also bump per-(b,j) reference counters for the CSR build.
// ---------------------------------------------------------------------------
template<int NCC>
__global__ __launch_bounds__(256) void knn_merge_kernel(
    const unsigned long long* __restrict__ partial,  // [BS*POOL][NCC*5]
    const float* __restrict__ vtx,                   // [BS][V][3]
    const int* __restrict__ sidx,                    // [POOL]
    int* __restrict__ nbr,                           // [BS*POOL][4]
    float* __restrict__ outv,                        // [BS][POOL][3]
    unsigned int* __restrict__ counts)               // [BS*V]
{
    const int t = blockIdx.x * 256 + threadIdx.x;    // 0..BS*POOL-1
    const int b = t / POOL;
    const int s = t % POOL;

    const unsigned long long* p = partial + (size_t)t * (NCC * 5);

    unsigned int h0 = ~0u, h1 = ~0u, h2 = ~0u, h3 = ~0u, h4 = ~0u;
    unsigned int l0 = 0, l1 = 0, l2 = 0, l3 = 0, l4 = 0;

#pragma unroll 4
    for (int ccc = 0; ccc < NCC; ++ccc) {
        const unsigned long long a0 = p[ccc * 5 + 0];
        const unsigned long long a1 = p[ccc * 5 + 1];
        const unsigned long long a2 = p[ccc * 5 + 2];
        const unsigned long long a3 = p[ccc * 5 + 3];
        const unsigned long long a4 = p[ccc * 5 + 4];
        if ((unsigned int)(a0 >> 32) < h4) {
#define INS(K)                                                               \
            {                                                                \
                const unsigned int u = (unsigned int)((K) >> 32);            \
                const unsigned int idx = (unsigned int)(K);                  \
                const bool c0 = u < h0, c1 = u < h1, c2 = u < h2,            \
                           c3 = u < h3, c4 = u < h4;                         \
                h4 = c4 ? (c3 ? h3 : u) : h4;                                \
                l4 = c4 ? (c3 ? l3 : idx) : l4;                              \
                h3 = c3 ? (c2 ? h2 : u) : h3;                                \
                l3 = c3 ? (c2 ? l2 : idx) : l3;                              \
                h2 = c2 ? (c1 ? h1 : u) : h2;                                \
                l2 = c2 ? (c1 ? l1 : idx) : l2;                              \
                h1 = c1 ? (c0 ? h0 : u) : h1;                                \
                l1 = c1 ? (c0 ? l0 : idx) : l1;                              \
                h0 = c0 ? u : h0;                                            \
                l0 = c0 ? idx : l0;                                          \
            }
            INS(a0) INS(a1) INS(a2) INS(a3) INS(a4)
#undef INS
        }
    }

    int4 nb;
    nb.x = (int)l1;
    nb.y = (int)l2;
    nb.z = (int)l3;
    nb.w = (int)l4;
    ((int4*)nbr)[t] = nb;

    unsigned int* cb = counts + b * V;
    atomicAdd(&cb[l1], 1u);
    atomicAdd(&cb[l2], 1u);
    atomicAdd(&cb[l3], 1u);
    atomicAdd(&cb[l4], 1u);

    const int gq = sidx[s];
    const float* vv = vtx + ((size_t)b * V + gq) * 3;
    outv[(size_t)t * 3 + 0] = vv[0];
    outv[(size_t)t * 3 + 1] = vv[1];
    outv[(size_t)t * 3 + 2] = vv[2];
}

// ---------------------------------------------------------------------------
// Kernel 3: per-batch exclusive scan of counts -> rowptr, then fill CSR
// entries using LDS cursors (fused; cursors never touch global).
// One block per batch.
// ---------------------------------------------------------------------------
__global__ __launch_bounds__(256) void scan_fill_kernel(
    const unsigned int* __restrict__ counts,   // [BS][V]
    const int* __restrict__ nbr,               // [BS*POOL][4]
    unsigned int* __restrict__ rowptr,         // [BS][V+1]
    unsigned int* __restrict__ entries)        // [BS][4096]
{
    const int b = blockIdx.x;
    const int tid = threadIdx.x;
    __shared__ unsigned int psum[256];
    __shared__ unsigned int cur[V];            // 16 KiB cursors

    const unsigned int* cb = counts + b * V;
    unsigned int local[16];
    unsigned int sum = 0;
#pragma unroll
    for (int i = 0; i < 16; ++i) { local[i] = sum; sum += cb[tid * 16 + i]; }
    psum[tid] = sum;
    __syncthreads();

    for (int off = 1; off < 256; off <<= 1) {
        unsigned int v = (tid >= off) ? psum[tid - off] : 0u;
        __syncthreads();
        psum[tid] += v;
        __syncthreads();
    }
    const unsigned int base = (tid == 0) ? 0u : psum[tid - 1];

    unsigned int* rp = rowptr + b * (V + 1);
#pragma unroll
    for (int i = 0; i < 16; ++i) {
        const unsigned int e = base + local[i];
        rp[tid * 16 + i] = e;
        cur[tid * 16 + i] = e;
    }
    if (tid == 255) rp[V] = base + sum;   // == 4096
    __syncthreads();

    unsigned int* en = entries + b * 4096;
#pragma unroll
    for (int it = 0; it < POOL / 256; ++it) {
        const int s = it * 256 + tid;
        const int4 nb = ((const int4*)nbr)[b * POOL + s];
        en[atomicAdd(&cur[nb.x], 1u)] = (unsigned int)s;
        en[atomicAdd(&cur[nb.y], 1u)] = (unsigned int)s;
        en[atomicAdd(&cur[nb.z], 1u)] = (unsigned int)s;
        en[atomicAdd(&cur[nb.w], 1u)] = (unsigned int)s;
    }
}

// ---------------------------------------------------------------------------
// Kernel 4: streaming scatter-max pool. Block = (b,c) plane; LDS holds the
// [POOL] x A output plane (row stride 13 words: gcd(13,32)=1 -> atomics
// spread across all 32 banks). Rows read in ascending-j order; unreferenced
// rows skipped.
// ---------------------------------------------------------------------------
__global__ __launch_bounds__(512) void pool_kernel(
    const float* __restrict__ fm,              // [BS][C][V][A]
    const unsigned int* __restrict__ rowptr,   // [BS][V+1]
    const unsigned int* __restrict__ entries,  // [BS][4096]
    float* __restrict__ outf)                  // [BS][C][POOL][A]
{
    __shared__ unsigned int pl[POOL * PSTRIDE];    // 53248 B
    const int c = blockIdx.x % C;
    const int b = blockIdx.x / C;
    const int tid = threadIdx.x;

    for (int i = tid; i < POOL * PSTRIDE; i += 512) pl[i] = 0u;  // 0 < ordu(any)
    __syncthreads();

    const unsigned int* rp = rowptr + b * (V + 1);
    const unsigned int* en = entries + b * 4096;
    const float4* plane = (const float4*)(fm + (size_t)(b * C + c) * V * A);

#pragma unroll 1
    for (int it = 0; it < V / 512; ++it) {
        const int j = it * 512 + tid;
        const unsigned int beg = rp[j];
        const unsigned int end = rp[j + 1];
        if (beg == end) continue;

        const float4 f0 = plane[j * 3 + 0];
        const float4 f1 = plane[j * 3 + 1];
        const float4 f2 = plane[j * 3 + 2];
        const unsigned int u0 = ordu(f0.x), u1 = ordu(f0.y), u2  = ordu(f0.z), u3  = ordu(f0.w);
        const unsigned int u4 = ordu(f1.x), u5 = ordu(f1.y), u6  = ordu(f1.z), u7  = ordu(f1.w);
        const unsigned int u8 = ordu(f2.x), u9 = ordu(f2.y), u10 = ordu(f2.z), u11 = ordu(f2.w);

        for (unsigned int e = beg; e < end; ++e) {
            unsigned int* d = pl + en[e] * PSTRIDE;
            atomicMax(d + 0, u0);  atomicMax(d + 1, u1);  atomicMax(d + 2, u2);
            atomicMax(d + 3, u3);  atomicMax(d + 4, u4);  atomicMax(d + 5, u5);
            atomicMax(d + 6, u6);  atomicMax(d + 7, u7);  atomicMax(d + 8, u8);
            atomicMax(d + 9, u9);  atomicMax(d + 10, u10); atomicMax(d + 11, u11);
        }
    }
    __syncthreads();

    float* dst = outf + (size_t)(b * C + c) * POOL * A;
#pragma unroll
    for (int it = 0; it < POOL / 512; ++it) {
        const int s = it * 512 + tid;
        const unsigned int* src = pl + s * PSTRIDE;
        float4 o0, o1, o2;
        o0.x = unordu(src[0]);  o0.y = unordu(src[1]);  o0.z = unordu(src[2]);  o0.w = unordu(src[3]);
        o1.x = unordu(src[4]);  o1.y = unordu(src[5]);  o1.z = unordu(src[6]);  o1.w = unordu(src[7]);
        o2.x = unordu(src[8]);  o2.y = unordu(src[9]);  o2.z = unordu(src[10]); o2.w = unordu(src[11]);
        float4* d4 = (float4*)(dst + (size_t)s * A);
        d4[0] = o0; d4[1] = o1; d4[2] = o2;
    }
}

// ---------------------------------------------------------------------------
extern "C" void kernel_launch(void* const* d_in, const int* in_sizes, int n_in,
                              void* d_out, int out_size, void* d_ws, size_t ws_size,
                              hipStream_t stream) {
    const float* vtx = (const float*)d_in[0];   // vertices  [BS][V][3]
    const float* fm  = (const float*)d_in[1];   // feature_map [BS][C][V][A]
    const int* sidx  = (const int*)d_in[2];     // sample_idx [POOL]
    float* out = (float*)d_out;

    float* outv = out;                          // [BS][POOL][3]
    float* outf = out + (size_t)BS * POOL * 3;  // [BS][C][POOL][A]

    char* ws = (char*)d_ws;
    const size_t partial32_b = (size_t)BS * POOL * 32 * 5 * 8;   // 10.5 MB
    const size_t partial16_b = (size_t)BS * POOL * 16 * 5 * 8;   // 5.2 MB
    const size_t nbr_b     = (size_t)BS * POOL * 4 * 4;          // 128 KB
    const size_t counts_b  = (size_t)BS * V * 4;                 // 128 KB
    const size_t rowptr_b  = (size_t)BS * (V + 1) * 4 + 32;      // pad
    const size_t entries_b = (size_t)BS * 4096 * 4;              // 128 KB
    const size_t tail_b = nbr_b + counts_b + rowptr_b + entries_b;

    const bool big = ws_size >= partial32_b + tail_b;
    const size_t partial_b = big ? partial32_b : partial16_b;

    unsigned long long* partial = (unsigned long long*)ws;
    int* nbr             = (int*)(ws + partial_b);
    unsigned int* counts = (unsigned int*)(ws + partial_b + nbr_b);
    unsigned int* rowptr = (unsigned int*)(ws + partial_b + nbr_b + counts_b);
    unsigned int* entries= (unsigned int*)(ws + partial_b + nbr_b + counts_b + rowptr_b);

    if (big) {
        constexpr int NCC = 32;
        knn_chunk_kernel<NCC><<<BS * 4 * NCC, 256, 0, stream>>>(vtx, sidx, partial, counts);
        knn_merge_kernel<NCC><<<(BS * POOL) / 256, 256, 0, stream>>>(partial, vtx, sidx, nbr, outv, counts);
    } else {
        constexpr int NCC = 16;
        knn_chunk_kernel<NCC><<<BS * 4 * NCC, 256, 0, stream>>>(vtx, sidx, partial, counts);
        knn_merge_kernel<NCC><<<(BS * POOL) / 256, 256, 0, stream>>>(partial, vtx, sidx, nbr, outv, counts);
    }
    scan_fill_kernel<<<BS, 256, 0, stream>>>(counts, nbr, rowptr, entries);
    pool_kernel<<<BS * C, 512, 0, stream>>>(fm, rowptr, entries, outf);
}